// Round 1
// baseline (134.644 us; speedup 1.0000x reference)
//
#include <hip/hip_runtime.h>
#include <hip/hip_bf16.h>

typedef __attribute__((ext_vector_type(8))) short bf16x8;
typedef __attribute__((ext_vector_type(4))) float f32x4;

__device__ __forceinline__ unsigned short f2bf(float f) {
  unsigned int u = __builtin_bit_cast(unsigned int, f);
  u += 0x7fffu + ((u >> 16) & 1u);
  return (unsigned short)(u >> 16);
}

__device__ __forceinline__ f32x4 mfma16(bf16x8 a, bf16x8 b, f32x4 c) {
  return __builtin_amdgcn_mfma_f32_16x16x32_bf16(a, b, c, 0, 0, 0);
}

// ---------------- K0: weight prep (fp32 -> bf16, padded) ----------------
// ws layout (elements of unsigned short):
//   w1b [256][704]  (k 676..703 zero)     offset 0
//   w2b [128][256]                        offset 256*704
//   w3b [64][128]                         + 128*256
//   w4b [16][64]    (rows 10..15 zero)    + 64*128
__global__ void prep_weights(const float* __restrict__ w1, const float* __restrict__ w2,
                             const float* __restrict__ w3, const float* __restrict__ w4,
                             unsigned short* __restrict__ w1b, unsigned short* __restrict__ w2b,
                             unsigned short* __restrict__ w3b, unsigned short* __restrict__ w4b) {
  const int idx = blockIdx.x * blockDim.x + threadIdx.x;
  const int stride = gridDim.x * blockDim.x;
  for (int i = idx; i < 256 * 704; i += stride) {
    int o = i / 704, k = i - o * 704;
    w1b[i] = f2bf(k < 676 ? w1[o * 676 + k] : 0.f);
  }
  for (int i = idx; i < 128 * 256; i += stride) w2b[i] = f2bf(w2[i]);
  for (int i = idx; i < 64 * 128; i += stride) w3b[i] = f2bf(w3[i]);
  for (int i = idx; i < 16 * 64; i += stride) {
    int o = i >> 6, k = i & 63;
    w4b[i] = f2bf(o < 10 ? w4[o * 64 + k] : 0.f);
  }
}

// ---------------- K1: fused conv + 4-layer MLP ----------------
// Block: 512 threads (8 waves), BM=64 batch rows. Grid: 256 blocks.
// LDS regions (bytes):
//   A @ 0      : hbT [64][712] (91136)  -> later w2s [128][264] (67584) -> later h3s [64][72] (9216)
//   B @ 91136  : w1s [256][40] (20480)  -> later h2s [64][136] (17408)  -> later w4s [16][72] (2304)
//   C @ 111616 : h1s [64][264] (33792)  -> later w3s [64][136] (17408)
// total 145408
#define LDS_TOTAL 145408

__global__ __launch_bounds__(512, 2) void fused_mlp(
    const float* __restrict__ x,          // [16384][784]
    const float* __restrict__ cw,         // [9]
    const unsigned short* __restrict__ w1b,  // [256][704]
    const unsigned short* __restrict__ w2b,  // [128][256]
    const unsigned short* __restrict__ w3b,  // [64][128]
    const unsigned short* __restrict__ w4b,  // [16][64]
    const float* __restrict__ b1, const float* __restrict__ b2,
    const float* __restrict__ b3, const float* __restrict__ b4,
    float* __restrict__ out)              // [16384][10]
{
  extern __shared__ char lds[];
  unsigned short* hbT = (unsigned short*)(lds);            // stride 712
  unsigned short* w1s = (unsigned short*)(lds + 91136);    // stride 40
  unsigned short* h1s = (unsigned short*)(lds + 111616);   // stride 264
  unsigned short* w2s = (unsigned short*)(lds);            // stride 264
  unsigned short* h2s = (unsigned short*)(lds + 91136);    // stride 136
  unsigned short* w3s = (unsigned short*)(lds + 111616);   // stride 136
  unsigned short* h3s = (unsigned short*)(lds);            // stride 72
  unsigned short* w4s = (unsigned short*)(lds + 91136);    // stride 72

  const int tid = threadIdx.x;
  const int lane = tid & 63;
  const int lane15 = lane & 15;
  const int kg = (lane >> 4) << 3;       // k sub-offset (0,8,16,24)
  const int w = tid >> 6;                // wave 0..7
  const int wr = w >> 2;                 // 0..1  (row half)
  const int wc = w & 3;                  // 0..3  (col quarter)
  const int row0 = blockIdx.x * 64;

  // ---- Phase 0: conv (3x3 VALID) -> hbT bf16 [64][704(+pad)] ----
  {
    const float c0 = cw[0], c1 = cw[1], c2 = cw[2];
    const float c3 = cw[3], c4 = cw[4], c5 = cw[5];
    const float c6 = cw[6], c7 = cw[7], c8 = cw[8];
    const float* xblk = x + (size_t)row0 * 784;
    for (int f = tid; f < 64 * 182; f += 512) {
      int rr = f / 182;
      int t = f - rr * 182;
      int i = t / 7;
      int jq = t - i * 7;
      int j0 = jq << 2;
      const float* xr = xblk + rr * 784 + i * 28 + j0;
      if (jq < 6) {
        float4 v00 = *(const float4*)(xr);
        float4 v01 = *(const float4*)(xr + 4);
        float4 v10 = *(const float4*)(xr + 28);
        float4 v11 = *(const float4*)(xr + 32);
        float4 v20 = *(const float4*)(xr + 56);
        float4 v21 = *(const float4*)(xr + 60);
        float r0[8] = {v00.x, v00.y, v00.z, v00.w, v01.x, v01.y, v01.z, v01.w};
        float r1[8] = {v10.x, v10.y, v10.z, v10.w, v11.x, v11.y, v11.z, v11.w};
        float r2[8] = {v20.x, v20.y, v20.z, v20.w, v21.x, v21.y, v21.z, v21.w};
        float o[4];
#pragma unroll
        for (int tt = 0; tt < 4; ++tt) {
          o[tt] = c0 * r0[tt] + c1 * r0[tt + 1] + c2 * r0[tt + 2]
                + c3 * r1[tt] + c4 * r1[tt + 1] + c5 * r1[tt + 2]
                + c6 * r2[tt] + c7 * r2[tt + 1] + c8 * r2[tt + 2];
        }
        unsigned int p0 = (unsigned)f2bf(o[0]) | ((unsigned)f2bf(o[1]) << 16);
        unsigned int p1 = (unsigned)f2bf(o[2]) | ((unsigned)f2bf(o[3]) << 16);
        unsigned int* dst = (unsigned int*)(hbT + rr * 712 + i * 26 + j0);
        dst[0] = p0;
        dst[1] = p1;
      } else {  // j0 == 24: outputs j=24,25 only (avoid reading past row end)
        float4 v0 = *(const float4*)(xr);
        float4 v1 = *(const float4*)(xr + 28);
        float4 v2 = *(const float4*)(xr + 56);
        float o0 = c0 * v0.x + c1 * v0.y + c2 * v0.z
                 + c3 * v1.x + c4 * v1.y + c5 * v1.z
                 + c6 * v2.x + c7 * v2.y + c8 * v2.z;
        float o1 = c0 * v0.y + c1 * v0.z + c2 * v0.w
                 + c3 * v1.y + c4 * v1.z + c5 * v1.w
                 + c6 * v2.y + c7 * v2.z + c8 * v2.w;
        unsigned int p0 = (unsigned)f2bf(o0) | ((unsigned)f2bf(o1) << 16);
        *(unsigned int*)(hbT + rr * 712 + i * 26 + 24) = p0;
      }
    }
    // zero-pad k = 676..703 (14 uints per row)
    for (int f = tid; f < 64 * 14; f += 512) {
      int rr = f / 14, u = f - rr * 14;
      *(unsigned int*)(hbT + rr * 712 + 676 + (u << 1)) = 0u;
    }
  }

  f32x4 acc1[2][4] = {};
  __syncthreads();

  // ---- GEMM1: [64][704] x w1^T -> [64][256], 22 k-steps of 32 ----
  for (int ks = 0; ks < 22; ++ks) {
    const int k0 = ks << 5;
    {
      int f = tid;
#pragma unroll
      for (int it = 0; it < 2; ++it, f += 512) {
        int o = f >> 2, part = f & 3;
        *(uint4*)(w1s + o * 40 + (part << 3)) =
            *(const uint4*)(w1b + o * 704 + k0 + (part << 3));
      }
    }
    __syncthreads();
    bf16x8 a0 = *(const bf16x8*)(hbT + (wr * 32 + lane15) * 712 + k0 + kg);
    bf16x8 a1 = *(const bf16x8*)(hbT + (wr * 32 + 16 + lane15) * 712 + k0 + kg);
    bf16x8 fb0 = *(const bf16x8*)(w1s + (wc * 64 + lane15) * 40 + kg);
    bf16x8 fb1 = *(const bf16x8*)(w1s + (wc * 64 + 16 + lane15) * 40 + kg);
    bf16x8 fb2 = *(const bf16x8*)(w1s + (wc * 64 + 32 + lane15) * 40 + kg);
    bf16x8 fb3 = *(const bf16x8*)(w1s + (wc * 64 + 48 + lane15) * 40 + kg);
    acc1[0][0] = mfma16(a0, fb0, acc1[0][0]);
    acc1[0][1] = mfma16(a0, fb1, acc1[0][1]);
    acc1[0][2] = mfma16(a0, fb2, acc1[0][2]);
    acc1[0][3] = mfma16(a0, fb3, acc1[0][3]);
    acc1[1][0] = mfma16(a1, fb0, acc1[1][0]);
    acc1[1][1] = mfma16(a1, fb1, acc1[1][1]);
    acc1[1][2] = mfma16(a1, fb2, acc1[1][2]);
    acc1[1][3] = mfma16(a1, fb3, acc1[1][3]);
    __syncthreads();
  }

  // ---- epilogue1: +b1, relu, bf16 -> h1s [64][264]; stage w2s [128][264] ----
  {
    const int rb = wr * 32 + ((lane >> 4) << 2);
    const int cb = wc * 64 + lane15;
#pragma unroll
    for (int n = 0; n < 4; ++n) {
      const int col = cb + n * 16;
      const float bias = b1[col];
#pragma unroll
      for (int m = 0; m < 2; ++m) {
#pragma unroll
        for (int r = 0; r < 4; ++r) {
          float v = acc1[m][n][r] + bias;
          v = v > 0.f ? v : 0.f;
          h1s[(rb + m * 16 + r) * 264 + col] = f2bf(v);
        }
      }
    }
  }
  {
    int f = tid;
#pragma unroll
    for (int it = 0; it < 8; ++it, f += 512) {
      int o = f >> 5, part = f & 31;
      *(uint4*)(w2s + o * 264 + (part << 3)) =
          *(const uint4*)(w2b + o * 256 + (part << 3));
    }
  }
  __syncthreads();

  // ---- GEMM2: [64][256] x w2^T -> [64][128] ----
  f32x4 acc2[2][2] = {};
  {
    const int ar = wr * 32 + lane15;
    const int bc = wc * 32 + lane15;
#pragma unroll
    for (int ks = 0; ks < 8; ++ks) {
      const int k0 = ks << 5;
      bf16x8 a0 = *(const bf16x8*)(h1s + ar * 264 + k0 + kg);
      bf16x8 a1 = *(const bf16x8*)(h1s + (ar + 16) * 264 + k0 + kg);
      bf16x8 fb0 = *(const bf16x8*)(w2s + bc * 264 + k0 + kg);
      bf16x8 fb1 = *(const bf16x8*)(w2s + (bc + 16) * 264 + k0 + kg);
      acc2[0][0] = mfma16(a0, fb0, acc2[0][0]);
      acc2[0][1] = mfma16(a0, fb1, acc2[0][1]);
      acc2[1][0] = mfma16(a1, fb0, acc2[1][0]);
      acc2[1][1] = mfma16(a1, fb1, acc2[1][1]);
    }
  }
  // epilogue2 -> h2s [64][136] (region B; w1s dead)
  {
    const int rb = wr * 32 + ((lane >> 4) << 2);
    const int cb2 = wc * 32 + lane15;
#pragma unroll
    for (int n = 0; n < 2; ++n) {
      const int col = cb2 + n * 16;
      const float bias = b2[col];
#pragma unroll
      for (int m = 0; m < 2; ++m) {
#pragma unroll
        for (int r = 0; r < 4; ++r) {
          float v = acc2[m][n][r] + bias;
          v = v > 0.f ? v : 0.f;
          h2s[(rb + m * 16 + r) * 136 + col] = f2bf(v);
        }
      }
    }
  }
  __syncthreads();
  // stage w3s [64][136] (region C; h1s dead)
  {
    int f = tid;
#pragma unroll
    for (int it = 0; it < 2; ++it, f += 512) {
      int o = f >> 4, part = f & 15;
      *(uint4*)(w3s + o * 136 + (part << 3)) =
          *(const uint4*)(w3b + o * 128 + (part << 3));
    }
  }
  __syncthreads();

  // ---- GEMM3: [64][128] x w3^T -> [64][64] ----
  f32x4 acc3[2] = {};
  {
    const int ar = wr * 32 + lane15;
    const int bc3 = wc * 16 + lane15;
#pragma unroll
    for (int ks = 0; ks < 4; ++ks) {
      const int k0 = ks << 5;
      bf16x8 a0 = *(const bf16x8*)(h2s + ar * 136 + k0 + kg);
      bf16x8 a1 = *(const bf16x8*)(h2s + (ar + 16) * 136 + k0 + kg);
      bf16x8 fb0 = *(const bf16x8*)(w3s + bc3 * 136 + k0 + kg);
      acc3[0] = mfma16(a0, fb0, acc3[0]);
      acc3[1] = mfma16(a1, fb0, acc3[1]);
    }
    // epilogue3 -> h3s [64][72] (region A; w2s dead)
    const int rb = wr * 32 + ((lane >> 4) << 2);
    const int col = bc3;
    const float bias = b3[col];
#pragma unroll
    for (int m = 0; m < 2; ++m) {
#pragma unroll
      for (int r = 0; r < 4; ++r) {
        float v = acc3[m][r] + bias;
        v = v > 0.f ? v : 0.f;
        h3s[(rb + m * 16 + r) * 72 + col] = f2bf(v);
      }
    }
  }
  __syncthreads();
  // stage w4s [16][72] (region B; h2s dead)
  if (tid < 128) {
    int o = tid >> 3, part = tid & 7;
    *(uint4*)(w4s + o * 72 + (part << 3)) =
        *(const uint4*)(w4b + o * 64 + (part << 3));
  }
  __syncthreads();

  // ---- GEMM4: [64][64] x w4^T -> [64][10], waves 0..3 only ----
  if (w < 4) {
    f32x4 acc4 = {};
    const int ar4 = w * 16 + lane15;
#pragma unroll
    for (int ks = 0; ks < 2; ++ks) {
      const int k0 = ks << 5;
      bf16x8 a0 = *(const bf16x8*)(h3s + ar4 * 72 + k0 + kg);
      bf16x8 fb0 = *(const bf16x8*)(w4s + lane15 * 72 + k0 + kg);
      acc4 = mfma16(a0, fb0, acc4);
    }
    const int col = lane15;
    if (col < 10) {
      const float bias = b4[col];
      const int rb4 = w * 16 + ((lane >> 4) << 2);
#pragma unroll
      for (int r = 0; r < 4; ++r) {
        out[(row0 + rb4 + r) * 10 + col] = acc4[r] + bias;
      }
    }
  }
}

extern "C" void kernel_launch(void* const* d_in, const int* in_sizes, int n_in,
                              void* d_out, int out_size, void* d_ws, size_t ws_size,
                              hipStream_t stream) {
  const float* x  = (const float*)d_in[0];
  const float* cw = (const float*)d_in[1];
  const float* w1 = (const float*)d_in[2];
  const float* b1 = (const float*)d_in[3];
  const float* w2 = (const float*)d_in[4];
  const float* b2 = (const float*)d_in[5];
  const float* w3 = (const float*)d_in[6];
  const float* b3 = (const float*)d_in[7];
  const float* w4 = (const float*)d_in[8];
  const float* b4 = (const float*)d_in[9];
  float* out = (float*)d_out;

  unsigned short* w1b = (unsigned short*)d_ws;          // 256*704
  unsigned short* w2b = w1b + 256 * 704;                // 128*256
  unsigned short* w3b = w2b + 128 * 256;                // 64*128
  unsigned short* w4b = w3b + 64 * 128;                 // 16*64

  hipLaunchKernelGGL(prep_weights, dim3(128), dim3(256), 0, stream,
                     w1, w2, w3, w4, w1b, w2b, w3b, w4b);

  hipFuncSetAttribute((const void*)fused_mlp,
                      hipFuncAttributeMaxDynamicSharedMemorySize, LDS_TOTAL);
  hipLaunchKernelGGL(fused_mlp, dim3(256), dim3(512), LDS_TOTAL, stream,
                     x, cw, w1b, w2b, w3b, w4b, b1, b2, b3, b4, out);
}